// Round 5
// baseline (650.160 us; speedup 1.0000x reference)
//
#include <hip/hip_runtime.h>
#include <hip/hip_bf16.h>

#define N_STORE 100000
#define N_DEPT  20000
#define F_IN    128
#define NTOT    (N_DEPT + 2 * N_STORE)   // combined CSR arena (rel0 | rel1 | rel2)

// bucketed CSR: rel0 buckets of 128 dept-nodes, rel1/2 buckets of 512 store-nodes
#define NB0   157                         // (20000+127)>>7
#define NB12  196                         // (100000+511)>>9
#define NBUCK (NB0 + 2 * NB12)            // 549

using u16    = unsigned short;
using bf16x8 = __attribute__((ext_vector_type(8))) __bf16;
using f32x4  = __attribute__((ext_vector_type(4))) float;

__device__ __forceinline__ float b2f(u16 x) {
    unsigned u = ((unsigned)x) << 16;
    return __builtin_bit_cast(float, u);
}
__device__ __forceinline__ u16 f2b(float f) {
    unsigned u = __builtin_bit_cast(unsigned, f);
    u += 0x7FFFu + ((u >> 16) & 1u);   // round-to-nearest-even
    return (u16)(u >> 16);
}

__global__ void k_zeroi(int* p, int n) {
    int i = blockIdx.x * 256 + threadIdx.x;
    if (i < n) p[i] = 0;
}

// ---------------- bucketed CSR build ----------------
__global__ void k_bcount(const int* __restrict__ e0, const int* __restrict__ e1,
                         const int* __restrict__ e2, int E, int* __restrict__ bucketCnt) {
    __shared__ int c[256];
    int t = threadIdx.x;
    c[t] = 0; __syncthreads();
    int rel = blockIdx.y;
    const int* e = (rel == 0) ? e0 : (rel == 1) ? e1 : e2;
    int n = (rel == 0) ? N_DEPT : N_STORE;
    int shift = (rel == 0) ? 7 : 9;
    int i0 = blockIdx.x * 2048 + t;
#pragma unroll
    for (int k = 0; k < 8; ++k) {
        int i = i0 + k * 256;
        if (i < E) {
            int d = e[E + i];
            if ((unsigned)d < (unsigned)n) atomicAdd(&c[d >> shift], 1);
        }
    }
    __syncthreads();
    int bbase = (rel == 0) ? 0 : (rel == 1) ? NB0 : NB0 + NB12;
    int nb = (rel == 0) ? NB0 : NB12;
    if (t < nb && c[t]) atomicAdd(&bucketCnt[bbase + t], c[t]);
}

__global__ void k_bscan(const int* __restrict__ bucketCnt, int* __restrict__ bucketOfs,
                        int* __restrict__ bucketCur, int* __restrict__ offs) {
    __shared__ int s[1024];
    int t = threadIdx.x;
    int v = (t < NBUCK) ? bucketCnt[t] : 0;
    s[t] = v; __syncthreads();
    for (int o = 1; o < 1024; o <<= 1) {
        int u = (t >= o) ? s[t - o] : 0;
        __syncthreads();
        s[t] += u;
        __syncthreads();
    }
    if (t < NBUCK) {
        bucketOfs[t + 1] = s[t];
        bucketCur[t] = s[t] - v;            // exclusive
    }
    if (t == 0) bucketOfs[0] = 0;
    if (t == NBUCK - 1) offs[NTOT] = s[t];  // sentinel = total pairs
}

__global__ void k_bscatter(const int* __restrict__ e0, const int* __restrict__ e1,
                           const int* __restrict__ e2, int E,
                           int* __restrict__ bucketCur, unsigned* __restrict__ pairs) {
    __shared__ int c[256];
    __shared__ int base[256];
    int t = threadIdx.x;
    c[t] = 0; __syncthreads();
    int rel = blockIdx.y;
    const int* e = (rel == 0) ? e0 : (rel == 1) ? e1 : e2;
    int n = (rel == 0) ? N_DEPT : N_STORE;
    int shift = (rel == 0) ? 7 : 9;
    int i0 = blockIdx.x * 2048 + t;
    int mb[8], mr[8]; unsigned mv[8];
#pragma unroll
    for (int k = 0; k < 8; ++k) {
        int i = i0 + k * 256;
        mb[k] = -1;
        if (i < E) {
            int d = e[E + i];
            if ((unsigned)d < (unsigned)n) {
                int b = d >> shift;
                mb[k] = b;
                mr[k] = atomicAdd(&c[b], 1);
                mv[k] = (unsigned)e[i] | ((unsigned)(d - (b << shift)) << 20);
            }
        }
    }
    __syncthreads();
    int bbase = (rel == 0) ? 0 : (rel == 1) ? NB0 : NB0 + NB12;
    int nb = (rel == 0) ? NB0 : NB12;
    if (t < nb && c[t]) base[t] = atomicAdd(&bucketCur[bbase + t], c[t]);
    __syncthreads();
#pragma unroll
    for (int k = 0; k < 8; ++k)
        if (mb[k] >= 0) pairs[base[mb[k]] + mr[k]] = mv[k];
}

__global__ void k_bfinal(const unsigned* __restrict__ pairs, const int* __restrict__ bucketOfs,
                         int* __restrict__ offs, int* __restrict__ srcs_all) {
    int b = blockIdx.x, t = threadIdx.x;
    int rel = (b < NB0) ? 0 : (b < NB0 + NB12) ? 1 : 2;
    int shift = (rel == 0) ? 7 : 9;
    int bLocal = b - ((rel == 0) ? 0 : (rel == 1) ? NB0 : NB0 + NB12);
    int n = (rel == 0) ? N_DEPT : N_STORE;
    int gbase = (rel == 0) ? 0 : (rel == 1) ? N_DEPT : N_DEPT + N_STORE;
    int nodeLo = bLocal << shift;
    int bsize = 1 << shift;
    int nNodes = n - nodeLo; if (nNodes > bsize) nNodes = bsize;
    int pairLo = bucketOfs[b], pairHi = bucketOfs[b + 1];
    __shared__ int cnt[512], sc[512];
    cnt[t] = 0; cnt[t + 256] = 0;
    __syncthreads();
    for (int p = pairLo + t; p < pairHi; p += 256)
        atomicAdd(&cnt[pairs[p] >> 20], 1);
    __syncthreads();
    sc[t] = cnt[t]; sc[t + 256] = cnt[t + 256];
    __syncthreads();
    for (int o = 1; o < 512; o <<= 1) {
        int a0 = (t >= o) ? sc[t - o] : 0;
        int a1 = (t + 256 >= o) ? sc[t + 256 - o] : 0;
        __syncthreads();
        sc[t] += a0; sc[t + 256] += a1;
        __syncthreads();
    }
    int ex0 = sc[t] - cnt[t];
    int ex1 = sc[t + 256] - cnt[t + 256];
    if (t < nNodes)       offs[gbase + nodeLo + t]       = pairLo + ex0;
    if (t + 256 < nNodes) offs[gbase + nodeLo + t + 256] = pairLo + ex1;
    __syncthreads();
    cnt[t] = ex0; cnt[t + 256] = ex1;     // reuse as cursors
    __syncthreads();
    for (int p = pairLo + t; p < pairHi; p += 256) {
        unsigned u = pairs[p];
        int q = atomicAdd(&cnt[u >> 20], 1);
        srcs_all[pairLo + q] = (int)(u & 0xFFFFFu);
    }
}

// ---------------- weight panel packing (MFMA B-fragment order), f32 -> bf16 ----
__global__ void k_pack_store(const float* __restrict__ Wa, const float* __restrict__ Wb,
                             const float* __restrict__ Wd1, const float* __restrict__ Wd2,
                             const float* __restrict__ aS0, const float* __restrict__ aS2,
                             const float* __restrict__ aD1, const float* __restrict__ aD2,
                             int K, u16* __restrict__ out) {
    int id = blockIdx.x * 256 + threadIdx.x;
    int total = K * 144;
    if (id >= total) return;
    int k = id / 144, n = id - k * 144;
    float val;
    if (n < 64) val = Wa[k * 64 + n];
    else if (n < 128) val = Wb[k * 64 + (n - 64)];
    else {
        int g = (n - 128) >> 2, h = (n - 128) & 3;
        const float* W = (g == 0) ? Wa : (g == 1) ? Wb : (g == 2) ? Wd1 : Wd2;
        const float* a = (g == 0) ? aS0 : (g == 1) ? aS2 : (g == 2) ? aD1 : aD2;
        float acc = 0.f;
        for (int c = 0; c < 16; ++c) acc += W[k * 64 + h * 16 + c] * a[h * 16 + c];
        val = acc;
    }
    int KT = K >> 5;
    int ct = n >> 4, col = n & 15, kt = k >> 5, q = (k >> 3) & 3, j = k & 7;
    out[(size_t)((ct * KT + kt) * 64 + q * 16 + col) * 8 + j] = f2b(val);
}

__global__ void k_pack_dept(const float* __restrict__ Ws1, const float* __restrict__ Wd0,
                            const float* __restrict__ aD0, const float* __restrict__ aS1,
                            int K, u16* __restrict__ out) {
    int id = blockIdx.x * 256 + threadIdx.x;
    int total = K * 80;
    if (id >= total) return;
    int k = id / 80, n = id - k * 80;
    float val;
    if (n < 64) val = Ws1[k * 64 + n];
    else if (n < 72) {
        int g = (n - 64) >> 2, h = (n - 64) & 3;
        const float* W = g ? Ws1 : Wd0;
        const float* a = g ? aS1 : aD0;
        float acc = 0.f;
        for (int c = 0; c < 16; ++c) acc += W[k * 64 + h * 16 + c] * a[h * 16 + c];
        val = acc;
    } else val = 0.f;
    int KT = K >> 5;
    int ct = n >> 4, col = n & 15, kt = k >> 5, q = (k >> 3) & 3, j = k & 7;
    out[(size_t)((ct * KT + kt) * 64 + q * 16 + col) * 8 + j] = f2b(val);
}

// ---------------- GEMM: wave per 16-row stripe; split-table epilogue ----------------
template <int KT, int CVT, int MODE>
__global__ void k_gemm(const void* __restrict__ Ain, int nrows, int K,
                       const u16* __restrict__ Bpanel,
                       u16* __restrict__ H0, u16* __restrict__ H1, u16* __restrict__ AL) {
    const int CT = (MODE == 0) ? 9 : 5;
    int wid = (blockIdx.x * blockDim.x + threadIdx.x) >> 6;
    int lane = threadIdx.x & 63;
    int m0 = wid << 4;
    if (m0 >= nrows) return;
    int r = lane & 15, q = lane >> 4;
    bf16x8 a[KT];
    if (CVT) {
        const float* ap = (const float*)Ain + (size_t)(m0 + r) * K + q * 8;
#pragma unroll
        for (int kt = 0; kt < KT; ++kt) {
            f32x4 f0 = *(const f32x4*)(ap + kt * 32);
            f32x4 f1 = *(const f32x4*)(ap + kt * 32 + 4);
            bf16x8 v;
#pragma unroll
            for (int j = 0; j < 4; ++j) {
                v[j]     = __builtin_bit_cast(__bf16, f2b(f0[j]));
                v[4 + j] = __builtin_bit_cast(__bf16, f2b(f1[j]));
            }
            a[kt] = v;
        }
    } else {
        const u16* ap = (const u16*)Ain + (size_t)(m0 + r) * K + q * 8;
#pragma unroll
        for (int kt = 0; kt < KT; ++kt) a[kt] = *(const bf16x8*)(ap + kt * 32);
    }
    const bf16x8* B = (const bf16x8*)Bpanel;
    int rowb = m0 + q * 4;
#pragma unroll
    for (int ct = 0; ct < CT; ++ct) {
        f32x4 acc = {0.f, 0.f, 0.f, 0.f};
#pragma unroll
        for (int kt = 0; kt < KT; ++kt)
            acc = __builtin_amdgcn_mfma_f32_16x16x32_bf16(a[kt], B[(ct * KT + kt) * 64 + lane], acc, 0, 0, 0);
        if (MODE == 0) {
            if (ct < 4) {
                u16* cp = H0 + (size_t)rowb * 64 + ct * 16 + r;
#pragma unroll
                for (int i = 0; i < 4; ++i) cp[(size_t)i * 64] = f2b(acc[i]);
            } else if (ct < 8) {
                u16* cp = H1 + (size_t)rowb * 64 + (ct - 4) * 16 + r;
#pragma unroll
                for (int i = 0; i < 4; ++i) cp[(size_t)i * 64] = f2b(acc[i]);
            } else {
                u16* cp = AL + (size_t)rowb * 16 + r;
#pragma unroll
                for (int i = 0; i < 4; ++i) cp[(size_t)i * 16] = f2b(acc[i]);
            }
        } else {
            if (ct < 4) {
                u16* cp = H0 + (size_t)rowb * 64 + ct * 16 + r;
#pragma unroll
                for (int i = 0; i < 4; ++i) cp[(size_t)i * 64] = f2b(acc[i]);
            } else {
                u16* cp = AL + (size_t)rowb * 16 + r;
#pragma unroll
                for (int i = 0; i < 4; ++i) cp[(size_t)i * 16] = f2b(acc[i]);
            }
        }
    }
}

// ---------------- aggregation helpers ----------------
__device__ __forceinline__ float warp16_sum(float v) {
    v += __shfl_xor(v, 1);
    v += __shfl_xor(v, 2);
    v += __shfl_xor(v, 4);
    v += __shfl_xor(v, 8);
    return v;
}

__device__ __forceinline__ void agg_seg(const int* __restrict__ srcs, int j0, int j1, int nsrc,
                                        const u16* __restrict__ htab, const u16* __restrict__ altab,
                                        int alsOff, int lane, int slot, int h, int pbase, float ald,
                                        float& acc, float& den) {
    for (int j = j0; j < j1; j += 16) {
        int nb = j1 - j; if (nb > 16) nb = 16;
        int sv = srcs[j + (slot < nb ? slot : 0)];
        sv = ((unsigned)sv < (unsigned)nsrc) ? sv : 0;
        u16 avr = altab[(size_t)sv * 16 + alsOff + h];
        float hv[16];
#pragma unroll
        for (int k = 0; k < 16; ++k) {
            int s = __builtin_amdgcn_readlane(sv, k);
            hv[k] = b2f(htab[(size_t)s * 64 + lane]);
        }
        float e = b2f(avr) + ald;
        e = (e > 0.f) ? e : 0.2f * e;
        float ex = (slot < nb) ? __expf(e) : 0.f;
        den += ex;
        int exi = __builtin_bit_cast(int, ex);
#pragma unroll
        for (int k = 0; k < 16; ++k) {
            float exv = __builtin_bit_cast(float,
                __builtin_amdgcn_ds_bpermute(pbase + (k << 2), exi));
            acc = fmaf(exv, hv[k], acc);
        }
    }
}

// ---------------- r0: store -> dept; 2 waves per node, LDS combine ----------------
__global__ void __launch_bounds__(256) k_agg1(
                       const int* __restrict__ offs, const int* __restrict__ srcs,
                       const u16* __restrict__ hS0, const u16* __restrict__ alS,
                       const u16* __restrict__ alD,
                       const float* __restrict__ bias, int doRelu,
                       u16* __restrict__ bOut, float* __restrict__ fOut) {
    __shared__ float sAcc[4][64];
    __shared__ float sDen[4][64];
    int wl = threadIdx.x >> 6;                                   // 0..3
    int gwid = (blockIdx.x * blockDim.x + threadIdx.x) >> 6;
    int node = gwid >> 1, half = gwid & 1;
    int lane = threadIdx.x & 63, slot = lane & 15, h = lane >> 4;
    int pbase = (lane & 48) << 2;
    float acc = 0.f, den = 0.f;
    bool active = node < N_DEPT;
    if (active) {
        float ald = b2f(alD[(size_t)node * 16 + 0 + h]);         // ald_r0
        int j0 = __builtin_amdgcn_readfirstlane(offs[node]);
        int j1 = __builtin_amdgcn_readfirstlane(offs[node + 1]);
        int cnt = j1 - j0;
        int mid = j0 + (((cnt + 31) >> 5) << 4);                 // 16-aligned half split
        if (mid > j1) mid = j1;
        int s = half ? mid : j0;
        int e = half ? j1 : mid;
        agg_seg(srcs, s, e, N_STORE, hS0, alS, 0, lane, slot, h, pbase, ald, acc, den);
        den = warp16_sum(den);
    }
    sAcc[wl][lane] = acc;
    sDen[wl][lane] = den;
    __syncthreads();
    if (active && half == 0) {
        float accT = acc + sAcc[wl + 1][lane];
        float denT = den + sDen[wl + 1][lane];
        float out = accT / (denT + 1e-16f) + bias[lane];
        if (doRelu) out = out > 0.f ? out : 0.f;
        size_t oi = (size_t)node * 64 + lane;
        if (fOut) fOut[oi] = out;
        else      bOut[oi] = f2b(out);
    }
}

// ---------------- fused r1+r2: interleaved dual-relation rounds ----------------
__global__ void k_agg2(const int* __restrict__ offs1, const int* __restrict__ srcs,
                       const int* __restrict__ offs2,
                       const u16* __restrict__ hD, const u16* __restrict__ alD,
                       const u16* __restrict__ hS2, const u16* __restrict__ alS,
                       const float* __restrict__ bias1, const float* __restrict__ bias2,
                       int doRelu,
                       u16* __restrict__ bOut, float* __restrict__ fOut) {
    int wid = (blockIdx.x * blockDim.x + threadIdx.x) >> 6;
    if (wid >= N_STORE) return;
    int lane = threadIdx.x & 63, slot = lane & 15, h = lane >> 4;
    int pbase = (lane & 48) << 2;
    float ald1 = b2f(alS[(size_t)wid * 16 + 8 + h]);      // ald_r1
    float ald2 = b2f(alS[(size_t)wid * 16 + 12 + h]);     // ald_r2
    int ja = __builtin_amdgcn_readfirstlane(offs1[wid]);
    int a1 = __builtin_amdgcn_readfirstlane(offs1[wid + 1]);
    int jb = __builtin_amdgcn_readfirstlane(offs2[wid]);
    int b1 = __builtin_amdgcn_readfirstlane(offs2[wid + 1]);
    float acc1 = 0.f, den1 = 0.f, acc2 = 0.f, den2 = 0.f;
    while (ja < a1 || jb < b1) {
        int nb1 = a1 - ja; nb1 = nb1 > 16 ? 16 : nb1;     // <=0 when r1 done
        int nb2 = b1 - jb; nb2 = nb2 > 16 ? 16 : nb2;
        int sv1 = 0, sv2 = 0;
        u16 av1 = 0, av2 = 0;
        // issue both srcs + both al gathers (independent)
        if (nb1 > 0) {
            int v = srcs[ja + (slot < nb1 ? slot : 0)];
            sv1 = ((unsigned)v < (unsigned)N_DEPT) ? v : 0;
            av1 = alD[(size_t)sv1 * 16 + 4 + h];          // als_r1
        }
        if (nb2 > 0) {
            int v = srcs[jb + (slot < nb2 ? slot : 0)];
            sv2 = ((unsigned)v < (unsigned)N_STORE) ? v : 0;
            av2 = alS[(size_t)sv2 * 16 + 4 + h];          // als_r2
        }
        // issue ALL 32 row gathers before any consumption
        u16 hv1[16], hv2[16];
        if (nb1 > 0) {
#pragma unroll
            for (int k = 0; k < 16; ++k) {
                int s = __builtin_amdgcn_readlane(sv1, k);
                hv1[k] = hD[(size_t)s * 64 + lane];
            }
        }
        if (nb2 > 0) {
#pragma unroll
            for (int k = 0; k < 16; ++k) {
                int s = __builtin_amdgcn_readlane(sv2, k);
                hv2[k] = hS2[(size_t)s * 64 + lane];
            }
        }
        int exi1 = 0, exi2 = 0;
        if (nb1 > 0) {
            float e = b2f(av1) + ald1;
            e = (e > 0.f) ? e : 0.2f * e;
            float ex = (slot < nb1) ? __expf(e) : 0.f;
            den1 += ex;
            exi1 = __builtin_bit_cast(int, ex);
        }
        if (nb2 > 0) {
            float e = b2f(av2) + ald2;
            e = (e > 0.f) ? e : 0.2f * e;
            float ex = (slot < nb2) ? __expf(e) : 0.f;
            den2 += ex;
            exi2 = __builtin_bit_cast(int, ex);
        }
        if (nb1 > 0) {
#pragma unroll
            for (int k = 0; k < 16; ++k) {
                float exv = __builtin_bit_cast(float,
                    __builtin_amdgcn_ds_bpermute(pbase + (k << 2), exi1));
                acc1 = fmaf(exv, b2f(hv1[k]), acc1);
            }
        }
        if (nb2 > 0) {
#pragma unroll
            for (int k = 0; k < 16; ++k) {
                float exv = __builtin_bit_cast(float,
                    __builtin_amdgcn_ds_bpermute(pbase + (k << 2), exi2));
                acc2 = fmaf(exv, b2f(hv2[k]), acc2);
            }
        }
        ja += 16; jb += 16;
    }
    den1 = warp16_sum(den1);
    den2 = warp16_sum(den2);
    float out = (acc1 / (den1 + 1e-16f) + bias1[lane] + acc2 / (den2 + 1e-16f) + bias2[lane]) * 0.5f;
    if (doRelu) out = out > 0.f ? out : 0.f;
    size_t oi = (size_t)wid * 64 + lane;
    if (fOut) fOut[oi] = out;
    else      bOut[oi] = f2b(out);
}

extern "C" void kernel_launch(void* const* d_in, const int* in_sizes, int n_in,
                              void* d_out, int out_size, void* d_ws, size_t ws_size,
                              hipStream_t stream) {
    const float* x_store = (const float*)d_in[0];
    const float* x_dept  = (const float*)d_in[1];
    const int* e_sd = (const int*)d_in[2];
    const int* e_ds = (const int*)d_in[3];
    const int* e_ss = (const int*)d_in[4];
    const float* W_src0  = (const float*)d_in[5];
    const float* W_dst0  = (const float*)d_in[6];
    const float* W_src_h = (const float*)d_in[7];
    const float* W_dst_h = (const float*)d_in[8];
    const float* att_src = (const float*)d_in[9];
    const float* att_dst = (const float*)d_in[10];
    const float* bias    = (const float*)d_in[11];
    const int E = in_sizes[2] / 2;

    // ---- workspace (~61 MB) ----
    char* w = (char*)d_ws;
    auto alloc = [&](size_t bytes) -> char* {
        char* p = w;
        w += (bytes + 255) & ~(size_t)255;
        return p;
    };
    int* offs_all  = (int*)alloc((size_t)(NTOT + 1) * 4);
    int* srcs_all  = (int*)alloc((size_t)3 * E * 4);
    int* bucketCnt = (int*)alloc(1024 * 4);
    int* bucketOfs = (int*)alloc(1024 * 4);
    int* bucketCur = (int*)alloc(1024 * 4);
    u16* panelS[3]; u16* panelD[3];
    for (int l = 0; l < 3; ++l) {
        int KT = (l == 0) ? 4 : 2;
        panelS[l] = (u16*)alloc((size_t)KT * 9 * 64 * 8 * 2);
        panelD[l] = (u16*)alloc((size_t)KT * 5 * 64 * 8 * 2);
    }
    u16* hS0   = (u16*)alloc((size_t)N_STORE * 64 * 2);   // h for r0 (128B rows)
    u16* hS2   = (u16*)alloc((size_t)N_STORE * 64 * 2);   // h for r2
    u16* alS   = (u16*)alloc((size_t)N_STORE * 16 * 2);   // [als0(4) als2(4) ald1(4) ald2(4)]
    u16* hD    = (u16*)alloc((size_t)N_DEPT * 64 * 2);    // h for r1
    u16* alD   = (u16*)alloc((size_t)N_DEPT * 16 * 2);    // [ald0(4) als1(4) 0(8)]
    u16* actSA = (u16*)alloc((size_t)N_STORE * 64 * 2);
    u16* actDA = (u16*)alloc((size_t)N_DEPT * 64 * 2);
    u16* actSB = actSA;                      // safe alias (stream-ordered)
    u16* actDB = actDA;
    unsigned* pairs = (unsigned*)hS0;        // 12 MB staging, dead before hS0 is written

    int* off_sd = offs_all;                      // n = N_DEPT
    int* off_ds = offs_all + N_DEPT;             // n = N_STORE
    int* off_ss = offs_all + N_DEPT + N_STORE;   // n = N_STORE

    float* outStoreF = (float*)d_out;                       // final output: f32
    float* outDeptF  = outStoreF + (size_t)N_STORE * 64;

    // ---- bucketed CSR build ----
    int ebl8 = (E + 2047) / 2048;
    k_zeroi<<<(NBUCK + 255) / 256, 256, 0, stream>>>(bucketCnt, NBUCK);
    k_bcount<<<dim3(ebl8, 3), 256, 0, stream>>>(e_sd, e_ds, e_ss, E, bucketCnt);
    k_bscan<<<1, 1024, 0, stream>>>(bucketCnt, bucketOfs, bucketCur, offs_all);
    k_bscatter<<<dim3(ebl8, 3), 256, 0, stream>>>(e_sd, e_ds, e_ss, E, bucketCur, pairs);
    k_bfinal<<<NBUCK, 256, 0, stream>>>(pairs, bucketOfs, offs_all, srcs_all);

    // ---- layers ----
    for (int l = 0; l < 3; ++l) {
        int K = (l == 0) ? 128 : 64;
        const float *Ws[3], *Wd[3], *aS[3], *aD[3];
        for (int rr = 0; rr < 3; ++rr) {
            Ws[rr] = (l == 0) ? W_src0 + (size_t)rr * 128 * 64
                              : W_src_h + (size_t)((l - 1) * 3 + rr) * 64 * 64;
            Wd[rr] = (l == 0) ? W_dst0 + (size_t)rr * 128 * 64
                              : W_dst_h + (size_t)((l - 1) * 3 + rr) * 64 * 64;
            aS[rr] = att_src + (size_t)(l * 3 + rr) * 64;
            aD[rr] = att_dst + (size_t)(l * 3 + rr) * 64;
        }
        k_pack_store<<<(K * 144 + 255) / 256, 256, 0, stream>>>(
            Ws[0], Ws[2], Wd[1], Wd[2], aS[0], aS[2], aD[1], aD[2], K, panelS[l]);
        k_pack_dept<<<(K * 80 + 255) / 256, 256, 0, stream>>>(
            Ws[1], Wd[0], aD[0], aS[1], K, panelD[l]);

        int gbS = (N_STORE / 16 * 64 + 255) / 256;
        int gbD = (N_DEPT / 16 * 64 + 255) / 256;
        if (l == 0) {
            k_gemm<4, 1, 0><<<gbS, 256, 0, stream>>>(x_store, N_STORE, K, panelS[l], hS0, hS2, alS);
            k_gemm<4, 1, 1><<<gbD, 256, 0, stream>>>(x_dept, N_DEPT, K, panelD[l], hD, nullptr, alD);
        } else if (l == 1) {
            k_gemm<2, 0, 0><<<gbS, 256, 0, stream>>>(actSA, N_STORE, K, panelS[l], hS0, hS2, alS);
            k_gemm<2, 0, 1><<<gbD, 256, 0, stream>>>(actDA, N_DEPT, K, panelD[l], hD, nullptr, alD);
        } else {
            k_gemm<2, 0, 0><<<gbS, 256, 0, stream>>>(actSB, N_STORE, K, panelS[l], hS0, hS2, alS);
            k_gemm<2, 0, 1><<<gbD, 256, 0, stream>>>(actDB, N_DEPT, K, panelD[l], hD, nullptr, alD);
        }

        int relu = (l < 2) ? 1 : 0;
        u16* bS = (l == 0) ? actSA : actSB;
        u16* bD = (l == 0) ? actDA : actDB;
        float* fS = (l == 2) ? outStoreF : nullptr;
        float* fD = (l == 2) ? outDeptF  : nullptr;
        // r0: store -> dept (final write), 2 waves per dept node
        k_agg1<<<N_DEPT / 2, 256, 0, stream>>>(
            off_sd, srcs_all, hS0, alS, alD,
            bias + (size_t)(l * 3 + 0) * 64, relu, bD, fD);
        // fused r1+r2 -> store output (single write), interleaved rounds
        k_agg2<<<N_STORE / 4, 256, 0, stream>>>(
            off_ds, srcs_all, off_ss,
            hD, alD, hS2, alS,
            bias + (size_t)(l * 3 + 1) * 64, bias + (size_t)(l * 3 + 2) * 64,
            relu, bS, fS);
    }
    (void)n_in; (void)out_size; (void)ws_size;
}

// Round 6
// 566.169 us; speedup vs baseline: 1.1483x; 1.1483x over previous
//
#include <hip/hip_runtime.h>
#include <hip/hip_bf16.h>

#define N_STORE 100000
#define N_DEPT  20000
#define F_IN    128
#define NTOT    (N_DEPT + 2 * N_STORE)   // combined CSR arena (rel0 | rel1 | rel2)

// bucketed CSR: rel0 buckets of 128 dept-nodes, rel1/2 buckets of 512 store-nodes
#define NB0   157                         // (20000+127)>>7
#define NB12  196                         // (100000+511)>>9
#define NBUCK (NB0 + 2 * NB12)            // 549

using u16    = unsigned short;
using bf16x8 = __attribute__((ext_vector_type(8))) __bf16;
using f32x4  = __attribute__((ext_vector_type(4))) float;

__device__ __forceinline__ float b2f(u16 x) {
    unsigned u = ((unsigned)x) << 16;
    return __builtin_bit_cast(float, u);
}
__device__ __forceinline__ u16 f2b(float f) {
    unsigned u = __builtin_bit_cast(unsigned, f);
    u += 0x7FFFu + ((u >> 16) & 1u);   // round-to-nearest-even
    return (u16)(u >> 16);
}

__global__ void k_zeroi(int* p, int n) {
    int i = blockIdx.x * 256 + threadIdx.x;
    if (i < n) p[i] = 0;
}

// ---------------- bucketed CSR build ----------------
__global__ void k_bcount(const int* __restrict__ e0, const int* __restrict__ e1,
                         const int* __restrict__ e2, int E, int* __restrict__ bucketCnt) {
    __shared__ int c[256];
    int t = threadIdx.x;
    c[t] = 0; __syncthreads();
    int rel = blockIdx.y;
    const int* e = (rel == 0) ? e0 : (rel == 1) ? e1 : e2;
    int n = (rel == 0) ? N_DEPT : N_STORE;
    int shift = (rel == 0) ? 7 : 9;
    int i0 = blockIdx.x * 2048 + t;
#pragma unroll
    for (int k = 0; k < 8; ++k) {
        int i = i0 + k * 256;
        if (i < E) {
            int d = e[E + i];
            if ((unsigned)d < (unsigned)n) atomicAdd(&c[d >> shift], 1);
        }
    }
    __syncthreads();
    int bbase = (rel == 0) ? 0 : (rel == 1) ? NB0 : NB0 + NB12;
    int nb = (rel == 0) ? NB0 : NB12;
    if (t < nb && c[t]) atomicAdd(&bucketCnt[bbase + t], c[t]);
}

__global__ void k_bscan(const int* __restrict__ bucketCnt, int* __restrict__ bucketOfs,
                        int* __restrict__ bucketCur, int* __restrict__ offs) {
    __shared__ int s[1024];
    int t = threadIdx.x;
    int v = (t < NBUCK) ? bucketCnt[t] : 0;
    s[t] = v; __syncthreads();
    for (int o = 1; o < 1024; o <<= 1) {
        int u = (t >= o) ? s[t - o] : 0;
        __syncthreads();
        s[t] += u;
        __syncthreads();
    }
    if (t < NBUCK) {
        bucketOfs[t + 1] = s[t];
        bucketCur[t] = s[t] - v;            // exclusive
    }
    if (t == 0) bucketOfs[0] = 0;
    if (t == NBUCK - 1) offs[NTOT] = s[t];  // sentinel = total pairs
}

__global__ void k_bscatter(const int* __restrict__ e0, const int* __restrict__ e1,
                           const int* __restrict__ e2, int E,
                           int* __restrict__ bucketCur, unsigned* __restrict__ pairs) {
    __shared__ int c[256];
    __shared__ int base[256];
    int t = threadIdx.x;
    c[t] = 0; __syncthreads();
    int rel = blockIdx.y;
    const int* e = (rel == 0) ? e0 : (rel == 1) ? e1 : e2;
    int n = (rel == 0) ? N_DEPT : N_STORE;
    int shift = (rel == 0) ? 7 : 9;
    int i0 = blockIdx.x * 2048 + t;
    int mb[8], mr[8]; unsigned mv[8];
#pragma unroll
    for (int k = 0; k < 8; ++k) {
        int i = i0 + k * 256;
        mb[k] = -1;
        if (i < E) {
            int d = e[E + i];
            if ((unsigned)d < (unsigned)n) {
                int b = d >> shift;
                mb[k] = b;
                mr[k] = atomicAdd(&c[b], 1);
                mv[k] = (unsigned)e[i] | ((unsigned)(d - (b << shift)) << 20);
            }
        }
    }
    __syncthreads();
    int bbase = (rel == 0) ? 0 : (rel == 1) ? NB0 : NB0 + NB12;
    int nb = (rel == 0) ? NB0 : NB12;
    if (t < nb && c[t]) base[t] = atomicAdd(&bucketCur[bbase + t], c[t]);
    __syncthreads();
#pragma unroll
    for (int k = 0; k < 8; ++k)
        if (mb[k] >= 0) pairs[base[mb[k]] + mr[k]] = mv[k];
}

__global__ void k_bfinal(const unsigned* __restrict__ pairs, const int* __restrict__ bucketOfs,
                         int* __restrict__ offs, int* __restrict__ srcs_all) {
    int b = blockIdx.x, t = threadIdx.x;
    int rel = (b < NB0) ? 0 : (b < NB0 + NB12) ? 1 : 2;
    int shift = (rel == 0) ? 7 : 9;
    int bLocal = b - ((rel == 0) ? 0 : (rel == 1) ? NB0 : NB0 + NB12);
    int n = (rel == 0) ? N_DEPT : N_STORE;
    int gbase = (rel == 0) ? 0 : (rel == 1) ? N_DEPT : N_DEPT + N_STORE;
    int nodeLo = bLocal << shift;
    int bsize = 1 << shift;
    int nNodes = n - nodeLo; if (nNodes > bsize) nNodes = bsize;
    int pairLo = bucketOfs[b], pairHi = bucketOfs[b + 1];
    __shared__ int cnt[512], sc[512];
    cnt[t] = 0; cnt[t + 256] = 0;
    __syncthreads();
    for (int p = pairLo + t; p < pairHi; p += 256)
        atomicAdd(&cnt[pairs[p] >> 20], 1);
    __syncthreads();
    sc[t] = cnt[t]; sc[t + 256] = cnt[t + 256];
    __syncthreads();
    for (int o = 1; o < 512; o <<= 1) {
        int a0 = (t >= o) ? sc[t - o] : 0;
        int a1 = (t + 256 >= o) ? sc[t + 256 - o] : 0;
        __syncthreads();
        sc[t] += a0; sc[t + 256] += a1;
        __syncthreads();
    }
    int ex0 = sc[t] - cnt[t];
    int ex1 = sc[t + 256] - cnt[t + 256];
    if (t < nNodes)       offs[gbase + nodeLo + t]       = pairLo + ex0;
    if (t + 256 < nNodes) offs[gbase + nodeLo + t + 256] = pairLo + ex1;
    __syncthreads();
    cnt[t] = ex0; cnt[t + 256] = ex1;     // reuse as cursors
    __syncthreads();
    for (int p = pairLo + t; p < pairHi; p += 256) {
        unsigned u = pairs[p];
        int q = atomicAdd(&cnt[u >> 20], 1);
        srcs_all[pairLo + q] = (int)(u & 0xFFFFFu);
    }
}

// ---------------- weight panel packing (MFMA B-fragment order), f32 -> bf16 ----
__global__ void k_pack_store(const float* __restrict__ Wa, const float* __restrict__ Wb,
                             const float* __restrict__ Wd1, const float* __restrict__ Wd2,
                             const float* __restrict__ aS0, const float* __restrict__ aS2,
                             const float* __restrict__ aD1, const float* __restrict__ aD2,
                             int K, u16* __restrict__ out) {
    int id = blockIdx.x * 256 + threadIdx.x;
    int total = K * 144;
    if (id >= total) return;
    int k = id / 144, n = id - k * 144;
    float val;
    if (n < 64) val = Wa[k * 64 + n];
    else if (n < 128) val = Wb[k * 64 + (n - 64)];
    else {
        int g = (n - 128) >> 2, h = (n - 128) & 3;
        const float* W = (g == 0) ? Wa : (g == 1) ? Wb : (g == 2) ? Wd1 : Wd2;
        const float* a = (g == 0) ? aS0 : (g == 1) ? aS2 : (g == 2) ? aD1 : aD2;
        float acc = 0.f;
        for (int c = 0; c < 16; ++c) acc += W[k * 64 + h * 16 + c] * a[h * 16 + c];
        val = acc;
    }
    int KT = K >> 5;
    int ct = n >> 4, col = n & 15, kt = k >> 5, q = (k >> 3) & 3, j = k & 7;
    out[(size_t)((ct * KT + kt) * 64 + q * 16 + col) * 8 + j] = f2b(val);
}

__global__ void k_pack_dept(const float* __restrict__ Ws1, const float* __restrict__ Wd0,
                            const float* __restrict__ aD0, const float* __restrict__ aS1,
                            int K, u16* __restrict__ out) {
    int id = blockIdx.x * 256 + threadIdx.x;
    int total = K * 80;
    if (id >= total) return;
    int k = id / 80, n = id - k * 80;
    float val;
    if (n < 64) val = Ws1[k * 64 + n];
    else if (n < 72) {
        int g = (n - 64) >> 2, h = (n - 64) & 3;
        const float* W = g ? Ws1 : Wd0;
        const float* a = g ? aS1 : aD0;
        float acc = 0.f;
        for (int c = 0; c < 16; ++c) acc += W[k * 64 + h * 16 + c] * a[h * 16 + c];
        val = acc;
    } else val = 0.f;
    int KT = K >> 5;
    int ct = n >> 4, col = n & 15, kt = k >> 5, q = (k >> 3) & 3, j = k & 7;
    out[(size_t)((ct * KT + kt) * 64 + q * 16 + col) * 8 + j] = f2b(val);
}

// ---------------- GEMM: wave per 16-row stripe; split-table epilogue ----------------
// MODE 0 (store): CT=9 -> H0, H1, then AL tile -> alsS0 | alsS2 | aldS12
// MODE 1 (dept):  CT=5 -> H0, then AL tile -> aldD0 | alsD1 | (zeros dropped)
template <int KT, int CVT, int MODE>
__global__ void k_gemm(const void* __restrict__ Ain, int nrows, int K,
                       const u16* __restrict__ Bpanel,
                       u16* __restrict__ H0, u16* __restrict__ H1,
                       u16* __restrict__ A0, u16* __restrict__ A1, u16* __restrict__ A2) {
    const int CT = (MODE == 0) ? 9 : 5;
    int wid = (blockIdx.x * blockDim.x + threadIdx.x) >> 6;
    int lane = threadIdx.x & 63;
    int m0 = wid << 4;
    if (m0 >= nrows) return;
    int r = lane & 15, q = lane >> 4;
    bf16x8 a[KT];
    if (CVT) {
        const float* ap = (const float*)Ain + (size_t)(m0 + r) * K + q * 8;
#pragma unroll
        for (int kt = 0; kt < KT; ++kt) {
            f32x4 f0 = *(const f32x4*)(ap + kt * 32);
            f32x4 f1 = *(const f32x4*)(ap + kt * 32 + 4);
            bf16x8 v;
#pragma unroll
            for (int j = 0; j < 4; ++j) {
                v[j]     = __builtin_bit_cast(__bf16, f2b(f0[j]));
                v[4 + j] = __builtin_bit_cast(__bf16, f2b(f1[j]));
            }
            a[kt] = v;
        }
    } else {
        const u16* ap = (const u16*)Ain + (size_t)(m0 + r) * K + q * 8;
#pragma unroll
        for (int kt = 0; kt < KT; ++kt) a[kt] = *(const bf16x8*)(ap + kt * 32);
    }
    const bf16x8* B = (const bf16x8*)Bpanel;
    int rowb = m0 + q * 4;
#pragma unroll
    for (int ct = 0; ct < CT; ++ct) {
        f32x4 acc = {0.f, 0.f, 0.f, 0.f};
#pragma unroll
        for (int kt = 0; kt < KT; ++kt)
            acc = __builtin_amdgcn_mfma_f32_16x16x32_bf16(a[kt], B[(ct * KT + kt) * 64 + lane], acc, 0, 0, 0);
        if (ct < 4) {
            u16* cp = H0 + (size_t)rowb * 64 + ct * 16 + r;
#pragma unroll
            for (int i = 0; i < 4; ++i) cp[(size_t)i * 64] = f2b(acc[i]);
        } else if (MODE == 0 && ct < 8) {
            u16* cp = H1 + (size_t)rowb * 64 + (ct - 4) * 16 + r;
#pragma unroll
            for (int i = 0; i < 4; ++i) cp[(size_t)i * 64] = f2b(acc[i]);
        } else {
            // AL tile: 16 cols -> small per-use tables
            if (r < 4) {
                u16* cp = A0 + (size_t)rowb * 4 + r;
#pragma unroll
                for (int i = 0; i < 4; ++i) cp[(size_t)i * 4] = f2b(acc[i]);
            } else if (r < 8) {
                u16* cp = A1 + (size_t)rowb * 4 + (r - 4);
#pragma unroll
                for (int i = 0; i < 4; ++i) cp[(size_t)i * 4] = f2b(acc[i]);
            } else if (MODE == 0) {
                u16* cp = A2 + (size_t)rowb * 8 + (r - 8);
#pragma unroll
                for (int i = 0; i < 4; ++i) cp[(size_t)i * 8] = f2b(acc[i]);
            }
            // MODE 1, r >= 8: packed zeros, dropped
        }
    }
}

// ---------------- aggregation (r4-proven structure, small al tables) ----------------
__device__ __forceinline__ float warp16_sum(float v) {
    v += __shfl_xor(v, 1);
    v += __shfl_xor(v, 2);
    v += __shfl_xor(v, 4);
    v += __shfl_xor(v, 8);
    return v;
}

// altab rows: 4 u16 (one value per head) -> table <= 0.8 MB, L2-resident
__device__ __forceinline__ void agg_seg(const int* __restrict__ srcs, int j0, int j1, int nsrc,
                                        const u16* __restrict__ htab, const u16* __restrict__ altab,
                                        int lane, int slot, int h, int pbase, float ald,
                                        float& acc, float& den) {
    for (int j = j0; j < j1; j += 16) {
        int nb = j1 - j; if (nb > 16) nb = 16;
        int sv = srcs[j + (slot < nb ? slot : 0)];
        sv = ((unsigned)sv < (unsigned)nsrc) ? sv : 0;
        u16 avr = altab[(size_t)sv * 4 + h];
        float hv[16];
#pragma unroll
        for (int k = 0; k < 16; ++k) {
            int s = __builtin_amdgcn_readlane(sv, k);
            hv[k] = b2f(htab[(size_t)s * 64 + lane]);
        }
        float e = b2f(avr) + ald;
        e = (e > 0.f) ? e : 0.2f * e;
        float ex = (slot < nb) ? __expf(e) : 0.f;
        den += ex;
        int exi = __builtin_bit_cast(int, ex);
#pragma unroll
        for (int k = 0; k < 16; ++k) {
            float exv = __builtin_bit_cast(float,
                __builtin_amdgcn_ds_bpermute(pbase + (k << 2), exi));
            acc = fmaf(exv, hv[k], acc);
        }
    }
}

// ---------------- r0: store -> dept; 2 waves per node, LDS combine ----------------
__global__ void __launch_bounds__(256) k_agg1(
                       const int* __restrict__ offs, const int* __restrict__ srcs,
                       const u16* __restrict__ hS0, const u16* __restrict__ alsS0,
                       const u16* __restrict__ aldD0,
                       const float* __restrict__ bias, int doRelu,
                       u16* __restrict__ bOut, float* __restrict__ fOut) {
    __shared__ float sAcc[4][64];
    __shared__ float sDen[4][64];
    int wl = threadIdx.x >> 6;                                   // 0..3
    int gwid = (blockIdx.x * blockDim.x + threadIdx.x) >> 6;
    int node = gwid >> 1, half = gwid & 1;
    int lane = threadIdx.x & 63, slot = lane & 15, h = lane >> 4;
    int pbase = (lane & 48) << 2;
    float acc = 0.f, den = 0.f;
    bool active = node < N_DEPT;
    if (active) {
        float ald = b2f(aldD0[(size_t)node * 4 + h]);            // streaming by node
        int j0 = __builtin_amdgcn_readfirstlane(offs[node]);
        int j1 = __builtin_amdgcn_readfirstlane(offs[node + 1]);
        int cnt = j1 - j0;
        int mid = j0 + (((cnt + 31) >> 5) << 4);                 // 16-aligned half split
        if (mid > j1) mid = j1;
        int s = half ? mid : j0;
        int e = half ? j1 : mid;
        agg_seg(srcs, s, e, N_STORE, hS0, alsS0, lane, slot, h, pbase, ald, acc, den);
        den = warp16_sum(den);
    }
    sAcc[wl][lane] = acc;
    sDen[wl][lane] = den;
    __syncthreads();
    if (active && half == 0) {
        float accT = acc + sAcc[wl + 1][lane];
        float denT = den + sDen[wl + 1][lane];
        float out = accT / (denT + 1e-16f) + bias[lane];
        if (doRelu) out = out > 0.f ? out : 0.f;
        size_t oi = (size_t)node * 64 + lane;
        if (fOut) fOut[oi] = out;
        else      bOut[oi] = f2b(out);
    }
}

// ---------------- fused r1+r2: dept->store + store->store, serial (r4-proven) ----
__global__ void k_agg2(const int* __restrict__ offs1, const int* __restrict__ srcs,
                       const int* __restrict__ offs2,
                       const u16* __restrict__ hD, const u16* __restrict__ alsD1,
                       const u16* __restrict__ hS2, const u16* __restrict__ alsS2,
                       const u16* __restrict__ aldS12,
                       const float* __restrict__ bias1, const float* __restrict__ bias2,
                       int doRelu,
                       u16* __restrict__ bOut, float* __restrict__ fOut) {
    int wid = (blockIdx.x * blockDim.x + threadIdx.x) >> 6;
    if (wid >= N_STORE) return;
    int lane = threadIdx.x & 63, slot = lane & 15, h = lane >> 4;
    int pbase = (lane & 48) << 2;
    float ald1 = b2f(aldS12[(size_t)wid * 8 + h]);        // streaming by wid
    float ald2 = b2f(aldS12[(size_t)wid * 8 + 4 + h]);
    int a0 = __builtin_amdgcn_readfirstlane(offs1[wid]);
    int a1e = __builtin_amdgcn_readfirstlane(offs1[wid + 1]);
    int b0 = __builtin_amdgcn_readfirstlane(offs2[wid]);
    int b1e = __builtin_amdgcn_readfirstlane(offs2[wid + 1]);
    float acc1 = 0.f, den1 = 0.f, acc2 = 0.f, den2 = 0.f;
    agg_seg(srcs, a0, a1e, N_DEPT, hD, alsD1, lane, slot, h, pbase, ald1, acc1, den1);
    agg_seg(srcs, b0, b1e, N_STORE, hS2, alsS2, lane, slot, h, pbase, ald2, acc2, den2);
    den1 = warp16_sum(den1);
    den2 = warp16_sum(den2);
    float out = (acc1 / (den1 + 1e-16f) + bias1[lane] + acc2 / (den2 + 1e-16f) + bias2[lane]) * 0.5f;
    if (doRelu) out = out > 0.f ? out : 0.f;
    size_t oi = (size_t)wid * 64 + lane;
    if (fOut) fOut[oi] = out;
    else      bOut[oi] = f2b(out);
}

extern "C" void kernel_launch(void* const* d_in, const int* in_sizes, int n_in,
                              void* d_out, int out_size, void* d_ws, size_t ws_size,
                              hipStream_t stream) {
    const float* x_store = (const float*)d_in[0];
    const float* x_dept  = (const float*)d_in[1];
    const int* e_sd = (const int*)d_in[2];
    const int* e_ds = (const int*)d_in[3];
    const int* e_ss = (const int*)d_in[4];
    const float* W_src0  = (const float*)d_in[5];
    const float* W_dst0  = (const float*)d_in[6];
    const float* W_src_h = (const float*)d_in[7];
    const float* W_dst_h = (const float*)d_in[8];
    const float* att_src = (const float*)d_in[9];
    const float* att_dst = (const float*)d_in[10];
    const float* bias    = (const float*)d_in[11];
    const int E = in_sizes[2] / 2;

    // ---- workspace (~61 MB) ----
    char* w = (char*)d_ws;
    auto alloc = [&](size_t bytes) -> char* {
        char* p = w;
        w += (bytes + 255) & ~(size_t)255;
        return p;
    };
    int* offs_all  = (int*)alloc((size_t)(NTOT + 1) * 4);
    int* srcs_all  = (int*)alloc((size_t)3 * E * 4);
    int* bucketCnt = (int*)alloc(1024 * 4);
    int* bucketOfs = (int*)alloc(1024 * 4);
    int* bucketCur = (int*)alloc(1024 * 4);
    u16* panelS[3]; u16* panelD[3];
    for (int l = 0; l < 3; ++l) {
        int KT = (l == 0) ? 4 : 2;
        panelS[l] = (u16*)alloc((size_t)KT * 9 * 64 * 8 * 2);
        panelD[l] = (u16*)alloc((size_t)KT * 5 * 64 * 8 * 2);
    }
    u16* hS0    = (u16*)alloc((size_t)N_STORE * 64 * 2);  // h for r0 (128B rows)
    u16* hS2    = (u16*)alloc((size_t)N_STORE * 64 * 2);  // h for r2
    u16* hD     = (u16*)alloc((size_t)N_DEPT * 64 * 2);   // h for r1
    u16* alsS0  = (u16*)alloc((size_t)N_STORE * 4 * 2);   // gathered by agg1 (0.8 MB)
    u16* alsS2  = (u16*)alloc((size_t)N_STORE * 4 * 2);   // gathered by agg2-r2 (0.8 MB)
    u16* aldS12 = (u16*)alloc((size_t)N_STORE * 8 * 2);   // streamed by agg2 (dst side)
    u16* aldD0  = (u16*)alloc((size_t)N_DEPT * 4 * 2);    // streamed by agg1 (dst side)
    u16* alsD1  = (u16*)alloc((size_t)N_DEPT * 4 * 2);    // gathered by agg2-r1 (0.16 MB)
    u16* actSA  = (u16*)alloc((size_t)N_STORE * 64 * 2);
    u16* actDA  = (u16*)alloc((size_t)N_DEPT * 64 * 2);
    u16* actSB  = actSA;                     // safe alias (stream-ordered)
    u16* actDB  = actDA;
    unsigned* pairs = (unsigned*)hS0;        // 12 MB staging, dead before hS0 is written

    int* off_sd = offs_all;                      // n = N_DEPT
    int* off_ds = offs_all + N_DEPT;             // n = N_STORE
    int* off_ss = offs_all + N_DEPT + N_STORE;   // n = N_STORE

    float* outStoreF = (float*)d_out;                       // final output: f32
    float* outDeptF  = outStoreF + (size_t)N_STORE * 64;

    // ---- bucketed CSR build ----
    int ebl8 = (E + 2047) / 2048;
    k_zeroi<<<(NBUCK + 255) / 256, 256, 0, stream>>>(bucketCnt, NBUCK);
    k_bcount<<<dim3(ebl8, 3), 256, 0, stream>>>(e_sd, e_ds, e_ss, E, bucketCnt);
    k_bscan<<<1, 1024, 0, stream>>>(bucketCnt, bucketOfs, bucketCur, offs_all);
    k_bscatter<<<dim3(ebl8, 3), 256, 0, stream>>>(e_sd, e_ds, e_ss, E, bucketCur, pairs);
    k_bfinal<<<NBUCK, 256, 0, stream>>>(pairs, bucketOfs, offs_all, srcs_all);

    // ---- layers ----
    for (int l = 0; l < 3; ++l) {
        int K = (l == 0) ? 128 : 64;
        const float *Ws[3], *Wd[3], *aS[3], *aD[3];
        for (int rr = 0; rr < 3; ++rr) {
            Ws[rr] = (l == 0) ? W_src0 + (size_t)rr * 128 * 64
                              : W_src_h + (size_t)((l - 1) * 3 + rr) * 64 * 64;
            Wd[rr] = (l == 0) ? W_dst0 + (size_t)rr * 128 * 64
                              : W_dst_h + (size_t)((l - 1) * 3 + rr) * 64 * 64;
            aS[rr] = att_src + (size_t)(l * 3 + rr) * 64;
            aD[rr] = att_dst + (size_t)(l * 3 + rr) * 64;
        }
        k_pack_store<<<(K * 144 + 255) / 256, 256, 0, stream>>>(
            Ws[0], Ws[2], Wd[1], Wd[2], aS[0], aS[2], aD[1], aD[2], K, panelS[l]);
        k_pack_dept<<<(K * 80 + 255) / 256, 256, 0, stream>>>(
            Ws[1], Wd[0], aD[0], aS[1], K, panelD[l]);

        int gbS = (N_STORE / 16 * 64 + 255) / 256;
        int gbD = (N_DEPT / 16 * 64 + 255) / 256;
        if (l == 0) {
            k_gemm<4, 1, 0><<<gbS, 256, 0, stream>>>(x_store, N_STORE, K, panelS[l],
                                                     hS0, hS2, alsS0, alsS2, aldS12);
            k_gemm<4, 1, 1><<<gbD, 256, 0, stream>>>(x_dept, N_DEPT, K, panelD[l],
                                                     hD, nullptr, aldD0, alsD1, nullptr);
        } else if (l == 1) {
            k_gemm<2, 0, 0><<<gbS, 256, 0, stream>>>(actSA, N_STORE, K, panelS[l],
                                                     hS0, hS2, alsS0, alsS2, aldS12);
            k_gemm<2, 0, 1><<<gbD, 256, 0, stream>>>(actDA, N_DEPT, K, panelD[l],
                                                     hD, nullptr, aldD0, alsD1, nullptr);
        } else {
            k_gemm<2, 0, 0><<<gbS, 256, 0, stream>>>(actSB, N_STORE, K, panelS[l],
                                                     hS0, hS2, alsS0, alsS2, aldS12);
            k_gemm<2, 0, 1><<<gbD, 256, 0, stream>>>(actDB, N_DEPT, K, panelD[l],
                                                     hD, nullptr, aldD0, alsD1, nullptr);
        }

        int relu = (l < 2) ? 1 : 0;
        u16* bS = (l == 0) ? actSA : actSB;
        u16* bD = (l == 0) ? actDA : actDB;
        float* fS = (l == 2) ? outStoreF : nullptr;
        float* fD = (l == 2) ? outDeptF  : nullptr;
        // r0: store -> dept (final write), 2 waves per dept node
        k_agg1<<<N_DEPT / 2, 256, 0, stream>>>(
            off_sd, srcs_all, hS0, alsS0, aldD0,
            bias + (size_t)(l * 3 + 0) * 64, relu, bD, fD);
        // fused r1+r2 -> store output (single write)
        k_agg2<<<N_STORE / 4, 256, 0, stream>>>(
            off_ds, srcs_all, off_ss,
            hD, alsD1, hS2, alsS2, aldS12,
            bias + (size_t)(l * 3 + 1) * 64, bias + (size_t)(l * 3 + 2) * 64,
            relu, bS, fS);
    }
    (void)n_in; (void)out_size; (void)ws_size;
}

// Round 8
// 562.638 us; speedup vs baseline: 1.1556x; 1.0063x over previous
//
#include <hip/hip_runtime.h>
#include <hip/hip_bf16.h>

#define N_STORE 100000
#define N_DEPT  20000
#define F_IN    128
#define NTOT    (N_DEPT + 2 * N_STORE)   // combined CSR arena (rel0 | rel1 | rel2)

// bucketed CSR: rel0 buckets of 128 dept-nodes, rel1/2 buckets of 512 store-nodes
#define NB0   157                         // (20000+127)>>7
#define NB12  196                         // (100000+511)>>9
#define NBUCK (NB0 + 2 * NB12)            // 549

using u16    = unsigned short;
using u16x4  = __attribute__((ext_vector_type(4))) unsigned short;
using u32x2  = __attribute__((ext_vector_type(2))) unsigned;
using bf16x8 = __attribute__((ext_vector_type(8))) __bf16;
using f32x4  = __attribute__((ext_vector_type(4))) float;

__device__ __forceinline__ float b2f(u16 x) {
    unsigned u = ((unsigned)x) << 16;
    return __builtin_bit_cast(float, u);
}
__device__ __forceinline__ u16 f2b(float f) {
    unsigned u = __builtin_bit_cast(unsigned, f);
    u += 0x7FFFu + ((u >> 16) & 1u);   // round-to-nearest-even
    return (u16)(u >> 16);
}

__global__ void k_zeroi(int* p, int n) {
    int i = blockIdx.x * 256 + threadIdx.x;
    if (i < n) p[i] = 0;
}

// ---------------- bucketed CSR build ----------------
__global__ void k_bcount(const int* __restrict__ e0, const int* __restrict__ e1,
                         const int* __restrict__ e2, int E, int* __restrict__ bucketCnt) {
    __shared__ int c[256];
    int t = threadIdx.x;
    c[t] = 0; __syncthreads();
    int rel = blockIdx.y;
    const int* e = (rel == 0) ? e0 : (rel == 1) ? e1 : e2;
    int n = (rel == 0) ? N_DEPT : N_STORE;
    int shift = (rel == 0) ? 7 : 9;
    int i0 = blockIdx.x * 2048 + t;
#pragma unroll
    for (int k = 0; k < 8; ++k) {
        int i = i0 + k * 256;
        if (i < E) {
            int d = e[E + i];
            if ((unsigned)d < (unsigned)n) atomicAdd(&c[d >> shift], 1);
        }
    }
    __syncthreads();
    int bbase = (rel == 0) ? 0 : (rel == 1) ? NB0 : NB0 + NB12;
    int nb = (rel == 0) ? NB0 : NB12;
    if (t < nb && c[t]) atomicAdd(&bucketCnt[bbase + t], c[t]);
}

__global__ void k_bscan(const int* __restrict__ bucketCnt, int* __restrict__ bucketOfs,
                        int* __restrict__ bucketCur, int* __restrict__ offs) {
    __shared__ int s[1024];
    int t = threadIdx.x;
    int v = (t < NBUCK) ? bucketCnt[t] : 0;
    s[t] = v; __syncthreads();
    for (int o = 1; o < 1024; o <<= 1) {
        int u = (t >= o) ? s[t - o] : 0;
        __syncthreads();
        s[t] += u;
        __syncthreads();
    }
    if (t < NBUCK) {
        bucketOfs[t + 1] = s[t];
        bucketCur[t] = s[t] - v;            // exclusive
    }
    if (t == 0) bucketOfs[0] = 0;
    if (t == NBUCK - 1) offs[NTOT] = s[t];  // sentinel = total pairs
}

__global__ void k_bscatter(const int* __restrict__ e0, const int* __restrict__ e1,
                           const int* __restrict__ e2, int E,
                           int* __restrict__ bucketCur, unsigned* __restrict__ pairs) {
    __shared__ int c[256];
    __shared__ int base[256];
    int t = threadIdx.x;
    c[t] = 0; __syncthreads();
    int rel = blockIdx.y;
    const int* e = (rel == 0) ? e0 : (rel == 1) ? e1 : e2;
    int n = (rel == 0) ? N_DEPT : N_STORE;
    int shift = (rel == 0) ? 7 : 9;
    int i0 = blockIdx.x * 2048 + t;
    int mb[8], mr[8]; unsigned mv[8];
#pragma unroll
    for (int k = 0; k < 8; ++k) {
        int i = i0 + k * 256;
        mb[k] = -1;
        if (i < E) {
            int d = e[E + i];
            if ((unsigned)d < (unsigned)n) {
                int b = d >> shift;
                mb[k] = b;
                mr[k] = atomicAdd(&c[b], 1);
                mv[k] = (unsigned)e[i] | ((unsigned)(d - (b << shift)) << 20);
            }
        }
    }
    __syncthreads();
    int bbase = (rel == 0) ? 0 : (rel == 1) ? NB0 : NB0 + NB12;
    int nb = (rel == 0) ? NB0 : NB12;
    if (t < nb && c[t]) base[t] = atomicAdd(&bucketCur[bbase + t], c[t]);
    __syncthreads();
#pragma unroll
    for (int k = 0; k < 8; ++k)
        if (mb[k] >= 0) pairs[base[mb[k]] + mr[k]] = mv[k];
}

__global__ void k_bfinal(const unsigned* __restrict__ pairs, const int* __restrict__ bucketOfs,
                         int* __restrict__ offs, int* __restrict__ srcs_all) {
    int b = blockIdx.x, t = threadIdx.x;
    int rel = (b < NB0) ? 0 : (b < NB0 + NB12) ? 1 : 2;
    int shift = (rel == 0) ? 7 : 9;
    int bLocal = b - ((rel == 0) ? 0 : (rel == 1) ? NB0 : NB0 + NB12);
    int n = (rel == 0) ? N_DEPT : N_STORE;
    int gbase = (rel == 0) ? 0 : (rel == 1) ? N_DEPT : N_DEPT + N_STORE;
    int nodeLo = bLocal << shift;
    int bsize = 1 << shift;
    int nNodes = n - nodeLo; if (nNodes > bsize) nNodes = bsize;
    int pairLo = bucketOfs[b], pairHi = bucketOfs[b + 1];
    __shared__ int cnt[512], sc[512];
    cnt[t] = 0; cnt[t + 256] = 0;
    __syncthreads();
    for (int p = pairLo + t; p < pairHi; p += 256)
        atomicAdd(&cnt[pairs[p] >> 20], 1);
    __syncthreads();
    sc[t] = cnt[t]; sc[t + 256] = cnt[t + 256];
    __syncthreads();
    for (int o = 1; o < 512; o <<= 1) {
        int a0 = (t >= o) ? sc[t - o] : 0;
        int a1 = (t + 256 >= o) ? sc[t + 256 - o] : 0;
        __syncthreads();
        sc[t] += a0; sc[t + 256] += a1;
        __syncthreads();
    }
    int ex0 = sc[t] - cnt[t];
    int ex1 = sc[t + 256] - cnt[t + 256];
    if (t < nNodes)       offs[gbase + nodeLo + t]       = pairLo + ex0;
    if (t + 256 < nNodes) offs[gbase + nodeLo + t + 256] = pairLo + ex1;
    __syncthreads();
    cnt[t] = ex0; cnt[t + 256] = ex1;     // reuse as cursors
    __syncthreads();
    for (int p = pairLo + t; p < pairHi; p += 256) {
        unsigned u = pairs[p];
        int q = atomicAdd(&cnt[u >> 20], 1);
        srcs_all[pairLo + q] = (int)(u & 0xFFFFFu);
    }
}

// ---------------- weight panel packing (MFMA B-fragment order), f32 -> bf16 ----
__global__ void k_pack_store(const float* __restrict__ Wa, const float* __restrict__ Wb,
                             const float* __restrict__ Wd1, const float* __restrict__ Wd2,
                             const float* __restrict__ aS0, const float* __restrict__ aS2,
                             const float* __restrict__ aD1, const float* __restrict__ aD2,
                             int K, u16* __restrict__ out) {
    int id = blockIdx.x * 256 + threadIdx.x;
    int total = K * 144;
    if (id >= total) return;
    int k = id / 144, n = id - k * 144;
    float val;
    if (n < 64) val = Wa[k * 64 + n];
    else if (n < 128) val = Wb[k * 64 + (n - 64)];
    else {
        int g = (n - 128) >> 2, h = (n - 128) & 3;
        const float* W = (g == 0) ? Wa : (g == 1) ? Wb : (g == 2) ? Wd1 : Wd2;
        const float* a = (g == 0) ? aS0 : (g == 1) ? aS2 : (g == 2) ? aD1 : aD2;
        float acc = 0.f;
        for (int c = 0; c < 16; ++c) acc += W[k * 64 + h * 16 + c] * a[h * 16 + c];
        val = acc;
    }
    int KT = K >> 5;
    int ct = n >> 4, col = n & 15, kt = k >> 5, q = (k >> 3) & 3, j = k & 7;
    out[(size_t)((ct * KT + kt) * 64 + q * 16 + col) * 8 + j] = f2b(val);
}

__global__ void k_pack_dept(const float* __restrict__ Ws1, const float* __restrict__ Wd0,
                            const float* __restrict__ aD0, const float* __restrict__ aS1,
                            int K, u16* __restrict__ out) {
    int id = blockIdx.x * 256 + threadIdx.x;
    int total = K * 80;
    if (id >= total) return;
    int k = id / 80, n = id - k * 80;
    float val;
    if (n < 64) val = Ws1[k * 64 + n];
    else if (n < 72) {
        int g = (n - 64) >> 2, h = (n - 64) & 3;
        const float* W = g ? Ws1 : Wd0;
        const float* a = g ? aS1 : aD0;
        float acc = 0.f;
        for (int c = 0; c < 16; ++c) acc += W[k * 64 + h * 16 + c] * a[h * 16 + c];
        val = acc;
    } else val = 0.f;
    int KT = K >> 5;
    int ct = n >> 4, col = n & 15, kt = k >> 5, q = (k >> 3) & 3, j = k & 7;
    out[(size_t)((ct * KT + kt) * 64 + q * 16 + col) * 8 + j] = f2b(val);
}

// ---------------- GEMM: wave per 16-row stripe; split-table epilogue ----------------
// MODE 0 (store): CT=9 -> H0, H1, then AL tile -> alsS0 | alsS2 | aldS12
// MODE 1 (dept):  CT=5 -> H0, then AL tile -> aldD0 | alsD1 | (zeros dropped)
template <int KT, int CVT, int MODE>
__global__ void k_gemm(const void* __restrict__ Ain, int nrows, int K,
                       const u16* __restrict__ Bpanel,
                       u16* __restrict__ H0, u16* __restrict__ H1,
                       u16* __restrict__ A0, u16* __restrict__ A1, u16* __restrict__ A2) {
    const int CT = (MODE == 0) ? 9 : 5;
    int wid = (blockIdx.x * blockDim.x + threadIdx.x) >> 6;
    int lane = threadIdx.x & 63;
    int m0 = wid << 4;
    if (m0 >= nrows) return;
    int r = lane & 15, q = lane >> 4;
    bf16x8 a[KT];
    if (CVT) {
        const float* ap = (const float*)Ain + (size_t)(m0 + r) * K + q * 8;
#pragma unroll
        for (int kt = 0; kt < KT; ++kt) {
            f32x4 f0 = *(const f32x4*)(ap + kt * 32);
            f32x4 f1 = *(const f32x4*)(ap + kt * 32 + 4);
            bf16x8 v;
#pragma unroll
            for (int j = 0; j < 4; ++j) {
                v[j]     = __builtin_bit_cast(__bf16, f2b(f0[j]));
                v[4 + j] = __builtin_bit_cast(__bf16, f2b(f1[j]));
            }
            a[kt] = v;
        }
    } else {
        const u16* ap = (const u16*)Ain + (size_t)(m0 + r) * K + q * 8;
#pragma unroll
        for (int kt = 0; kt < KT; ++kt) a[kt] = *(const bf16x8*)(ap + kt * 32);
    }
    const bf16x8* B = (const bf16x8*)Bpanel;
    int rowb = m0 + q * 4;
#pragma unroll
    for (int ct = 0; ct < CT; ++ct) {
        f32x4 acc = {0.f, 0.f, 0.f, 0.f};
#pragma unroll
        for (int kt = 0; kt < KT; ++kt)
            acc = __builtin_amdgcn_mfma_f32_16x16x32_bf16(a[kt], B[(ct * KT + kt) * 64 + lane], acc, 0, 0, 0);
        if (ct < 4) {
            u16* cp = H0 + (size_t)rowb * 64 + ct * 16 + r;
#pragma unroll
            for (int i = 0; i < 4; ++i) cp[(size_t)i * 64] = f2b(acc[i]);
        } else if (MODE == 0 && ct < 8) {
            u16* cp = H1 + (size_t)rowb * 64 + (ct - 4) * 16 + r;
#pragma unroll
            for (int i = 0; i < 4; ++i) cp[(size_t)i * 64] = f2b(acc[i]);
        } else {
            // AL tile: 16 cols -> small per-use tables
            if (r < 4) {
                u16* cp = A0 + (size_t)rowb * 4 + r;
#pragma unroll
                for (int i = 0; i < 4; ++i) cp[(size_t)i * 4] = f2b(acc[i]);
            } else if (r < 8) {
                u16* cp = A1 + (size_t)rowb * 4 + (r - 4);
#pragma unroll
                for (int i = 0; i < 4; ++i) cp[(size_t)i * 4] = f2b(acc[i]);
            } else if (MODE == 0) {
                u16* cp = A2 + (size_t)rowb * 8 + (r - 8);
#pragma unroll
                for (int i = 0; i < 4; ++i) cp[(size_t)i * 8] = f2b(acc[i]);
            }
            // MODE 1, r >= 8: packed zeros, dropped
        }
    }
}

// ---------------- aggregation: quad-edge dword2 gathers ----------------
// Phase A lane map: slot=lane&15 (edge), h=lane>>4 (head) -> ex once per (edge,head).
// Phase B lane map: lane handles channels [4*slot..4*slot+4) of edges {4k+h}.
// Per 16-edge round: 1 srcs load + 1 al gather + <=4 quad-row gathers (dwordx2/lane)
// + 8 bpermutes. Trailing empty quads skipped wave-uniformly.
__device__ __forceinline__ float warp16_sum(float v) {
    v += __shfl_xor(v, 1);
    v += __shfl_xor(v, 2);
    v += __shfl_xor(v, 4);
    v += __shfl_xor(v, 8);
    return v;
}

__device__ __forceinline__ void agg_seg(const int* __restrict__ srcs, int j0, int j1, int nsrc,
                                        const u16* __restrict__ htab, const u16* __restrict__ altab,
                                        int slot, int h, int qoff, int cexo, int choff,
                                        float ald, f32x4& acc, float& den) {
    for (int j = j0; j < j1; j += 16) {
        int nb = j1 - j; if (nb > 16) nb = 16;
        int sv = srcs[j + (slot < nb ? slot : 0)];
        sv = ((unsigned)sv < (unsigned)nsrc) ? sv : 0;
        u16 avr = altab[(size_t)sv * 4 + h];
        float e = b2f(avr) + ald;
        e = (e > 0.f) ? e : 0.2f * e;
        float ex = (slot < nb) ? __expf(e) : 0.f;
        den += ex;
        int exi = __builtin_bit_cast(int, ex);
        // phase B: row index broadcast (edge 4k+h) via bpermute
        int rowv[4];
#pragma unroll
        for (int k = 0; k < 4; ++k)
            if (4 * k < nb)
                rowv[k] = __builtin_amdgcn_ds_bpermute(qoff + (k << 4), sv);
        u32x2 dv[4];
#pragma unroll
        for (int k = 0; k < 4; ++k)
            if (4 * k < nb)
                dv[k] = *(const u32x2*)(htab + ((size_t)(unsigned)rowv[k] << 6) + choff);
        float exv[4];
#pragma unroll
        for (int k = 0; k < 4; ++k)
            if (4 * k < nb)
                exv[k] = __builtin_bit_cast(float,
                    __builtin_amdgcn_ds_bpermute(qoff + cexo + (k << 4), exi));
#pragma unroll
        for (int k = 0; k < 4; ++k)
            if (4 * k < nb) {
                acc[0] = fmaf(exv[k], __builtin_bit_cast(float, dv[k][0] << 16), acc[0]);
                acc[1] = fmaf(exv[k], __builtin_bit_cast(float, dv[k][0] & 0xFFFF0000u), acc[1]);
                acc[2] = fmaf(exv[k], __builtin_bit_cast(float, dv[k][1] << 16), acc[2]);
                acc[3] = fmaf(exv[k], __builtin_bit_cast(float, dv[k][1] & 0xFFFF0000u), acc[3]);
            }
    }
}

// cross-quarter reduction: sum partials over the 4 lane-quarters
__device__ __forceinline__ void quad_reduce(f32x4& a) {
#pragma unroll
    for (int i = 0; i < 4; ++i) {
        a[i] += __shfl_xor(a[i], 16);
        a[i] += __shfl_xor(a[i], 32);
    }
}

// ---------------- r0: store -> dept; 2 waves per node, LDS combine ----------------
__global__ void __launch_bounds__(256) k_agg1(
                       const int* __restrict__ offs, const int* __restrict__ srcs,
                       const u16* __restrict__ hS0, const u16* __restrict__ alsS0,
                       const u16* __restrict__ aldD0,
                       const float* __restrict__ bias, int doRelu,
                       u16* __restrict__ bOut, float* __restrict__ fOut) {
    __shared__ f32x4 sAcc[4][64];
    __shared__ float sDen[4][64];
    int wl = threadIdx.x >> 6;                                   // 0..3
    int gwid = (blockIdx.x * blockDim.x + threadIdx.x) >> 6;
    int node = gwid >> 1, half = gwid & 1;
    int lane = threadIdx.x & 63, slot = lane & 15, h = lane >> 4;
    int qoff = h << 2;                  // quarter == h
    int cexo = (slot >> 2) << 6;        // head-of-channel-quad offset for ex bpermute
    int choff = slot << 2;              // u16 offset of this lane's channel quad
    f32x4 acc = {0.f, 0.f, 0.f, 0.f};
    float den = 0.f;
    float ald = b2f(aldD0[(size_t)node * 4 + h]);            // streaming by node
    int j0 = __builtin_amdgcn_readfirstlane(offs[node]);
    int j1 = __builtin_amdgcn_readfirstlane(offs[node + 1]);
    int cnt = j1 - j0;
    int mid = j0 + (((cnt + 31) >> 5) << 4);                 // 16-aligned half split
    if (mid > j1) mid = j1;
    int s = half ? mid : j0;
    int e = half ? j1 : mid;
    agg_seg(srcs, s, e, N_STORE, hS0, alsS0, slot, h, qoff, cexo, choff, ald, acc, den);
    den = warp16_sum(den);
    quad_reduce(acc);
    // FULL-EXEC shfl: den for the head owning this lane's channel quad
    float dOwn = __shfl(den, (slot >> 2) << 4);
    sAcc[wl][lane] = acc;
    sDen[wl][lane] = den;
    __syncthreads();
    if (half == 0 && lane < 16) {
        f32x4 accO = sAcc[wl + 1][lane];
        float dT = dOwn + sDen[wl + 1][(slot >> 2) << 4];
        f32x4 b4 = ((const f32x4*)bias)[slot];
        f32x4 o;
#pragma unroll
        for (int i = 0; i < 4; ++i) {
            float v = (acc[i] + accO[i]) / (dT + 1e-16f) + b4[i];
            o[i] = doRelu ? (v > 0.f ? v : 0.f) : v;
        }
        if (fOut) ((f32x4*)fOut)[(size_t)node * 16 + slot] = o;
        else {
            u16x4 p;
#pragma unroll
            for (int i = 0; i < 4; ++i) p[i] = f2b(o[i]);
            ((u16x4*)bOut)[(size_t)node * 16 + slot] = p;
        }
    }
}

// ---------------- fused r1+r2: dept->store + store->store, single write ----------
__global__ void k_agg2(const int* __restrict__ offs1, const int* __restrict__ srcs,
                       const int* __restrict__ offs2,
                       const u16* __restrict__ hD, const u16* __restrict__ alsD1,
                       const u16* __restrict__ hS2, const u16* __restrict__ alsS2,
                       const u16* __restrict__ aldS12,
                       const float* __restrict__ bias1, const float* __restrict__ bias2,
                       int doRelu,
                       u16* __restrict__ bOut, float* __restrict__ fOut) {
    int wid = (blockIdx.x * blockDim.x + threadIdx.x) >> 6;
    if (wid >= N_STORE) return;
    int lane = threadIdx.x & 63, slot = lane & 15, h = lane >> 4;
    int qoff = h << 2;
    int cexo = (slot >> 2) << 6;
    int choff = slot << 2;
    float ald1 = b2f(aldS12[(size_t)wid * 8 + h]);        // streaming by wid
    float ald2 = b2f(aldS12[(size_t)wid * 8 + 4 + h]);
    int a0 = __builtin_amdgcn_readfirstlane(offs1[wid]);
    int a1e = __builtin_amdgcn_readfirstlane(offs1[wid + 1]);
    int b0 = __builtin_amdgcn_readfirstlane(offs2[wid]);
    int b1e = __builtin_amdgcn_readfirstlane(offs2[wid + 1]);
    f32x4 acc1 = {0.f, 0.f, 0.f, 0.f}, acc2 = {0.f, 0.f, 0.f, 0.f};
    float den1 = 0.f, den2 = 0.f;
    agg_seg(srcs, a0, a1e, N_DEPT, hD, alsD1, slot, h, qoff, cexo, choff, ald1, acc1, den1);
    agg_seg(srcs, b0, b1e, N_STORE, hS2, alsS2, slot, h, qoff, cexo, choff, ald2, acc2, den2);
    den1 = warp16_sum(den1);
    den2 = warp16_sum(den2);
    quad_reduce(acc1);
    quad_reduce(acc2);
    int denLane = (slot >> 2) << 4;
    float d1 = __shfl(den1, denLane);      // full exec
    float d2 = __shfl(den2, denLane);      // full exec
    if (lane < 16) {
        f32x4 b1 = ((const f32x4*)bias1)[slot];
        f32x4 b2 = ((const f32x4*)bias2)[slot];
        f32x4 o;
#pragma unroll
        for (int i = 0; i < 4; ++i) {
            float v = (acc1[i] / (d1 + 1e-16f) + b1[i] + acc2[i] / (d2 + 1e-16f) + b2[i]) * 0.5f;
            o[i] = doRelu ? (v > 0.f ? v : 0.f) : v;
        }
        if (fOut) ((f32x4*)fOut)[(size_t)wid * 16 + slot] = o;
        else {
            u16x4 p;
#pragma unroll
            for (int i = 0; i < 4; ++i) p[i] = f2b(o[i]);
            ((u16x4*)bOut)[(size_t)wid * 16 + slot] = p;
        }
    }
}

extern "C" void kernel_launch(void* const* d_in, const int* in_sizes, int n_in,
                              void* d_out, int out_size, void* d_ws, size_t ws_size,
                              hipStream_t stream) {
    const float* x_store = (const float*)d_in[0];
    const float* x_dept  = (const float*)d_in[1];
    const int* e_sd = (const int*)d_in[2];
    const int* e_ds = (const int*)d_in[3];
    const int* e_ss = (const int*)d_in[4];
    const float* W_src0  = (const float*)d_in[5];
    const float* W_dst0  = (const float*)d_in[6];
    const float* W_src_h = (const float*)d_in[7];
    const float* W_dst_h = (const float*)d_in[8];
    const float* att_src = (const float*)d_in[9];
    const float* att_dst = (const float*)d_in[10];
    const float* bias    = (const float*)d_in[11];
    const int E = in_sizes[2] / 2;

    // ---- workspace (~61 MB) ----
    char* w = (char*)d_ws;
    auto alloc = [&](size_t bytes) -> char* {
        char* p = w;
        w += (bytes + 255) & ~(size_t)255;
        return p;
    };
    int* offs_all  = (int*)alloc((size_t)(NTOT + 1) * 4);
    int* srcs_all  = (int*)alloc((size_t)3 * E * 4);
    int* bucketCnt = (int*)alloc(1024 * 4);
    int* bucketOfs = (int*)alloc(1024 * 4);
    int* bucketCur = (int*)alloc(1024 * 4);
    u16* panelS[3]; u16* panelD[3];
    for (int l = 0; l < 3; ++l) {
        int KT = (l == 0) ? 4 : 2;
        panelS[l] = (u16*)alloc((size_t)KT * 9 * 64 * 8 * 2);
        panelD[l] = (u16*)alloc((size_t)KT * 5 * 64 * 8 * 2);
    }
    u16* hS0    = (u16*)alloc((size_t)N_STORE * 64 * 2);  // h for r0 (128B rows)
    u16* hS2    = (u16*)alloc((size_t)N_STORE * 64 * 2);  // h for r2
    u16* hD     = (u16*)alloc((size_t)N_DEPT * 64 * 2);   // h for r1
    u16* alsS0  = (u16*)alloc((size_t)N_STORE * 4 * 2);   // gathered by agg1 (0.8 MB)
    u16* alsS2  = (u16*)alloc((size_t)N_STORE * 4 * 2);   // gathered by agg2-r2 (0.8 MB)
    u16* aldS12 = (u16*)alloc((size_t)N_STORE * 8 * 2);   // streamed by agg2 (dst side)
    u16* aldD0  = (u16*)alloc((size_t)N_DEPT * 4 * 2);    // streamed by agg1 (dst side)
    u16* alsD1  = (u16*)alloc((size_t)N_DEPT * 4 * 2);    // gathered by agg2-r1 (0.16 MB)
    u16* actSA  = (u16*)alloc((size_t)N_STORE * 64 * 2);
    u16* actDA  = (u16*)alloc((size_t)N_DEPT * 64 * 2);
    u16* actSB  = actSA;                     // safe alias (stream-ordered)
    u16* actDB  = actDA;
    unsigned* pairs = (unsigned*)hS0;        // 12 MB staging, dead before hS0 is written

    int* off_sd = offs_all;                      // n = N_DEPT
    int* off_ds = offs_all + N_DEPT;             // n = N_STORE
    int* off_ss = offs_all + N_DEPT + N_STORE;   // n = N_STORE

    float* outStoreF = (float*)d_out;                       // final output: f32
    float* outDeptF  = outStoreF + (size_t)N_STORE * 64;

    // ---- bucketed CSR build ----
    int ebl8 = (E + 2047) / 2048;
    k_zeroi<<<(NBUCK + 255) / 256, 256, 0, stream>>>(bucketCnt, NBUCK);
    k_bcount<<<dim3(ebl8, 3), 256, 0, stream>>>(e_sd, e_ds, e_ss, E, bucketCnt);
    k_bscan<<<1, 1024, 0, stream>>>(bucketCnt, bucketOfs, bucketCur, offs_all);
    k_bscatter<<<dim3(ebl8, 3), 256, 0, stream>>>(e_sd, e_ds, e_ss, E, bucketCur, pairs);
    k_bfinal<<<NBUCK, 256, 0, stream>>>(pairs, bucketOfs, offs_all, srcs_all);

    // ---- layers ----
    for (int l = 0; l < 3; ++l) {
        int K = (l == 0) ? 128 : 64;
        const float *Ws[3], *Wd[3], *aS[3], *aD[3];
        for (int rr = 0; rr < 3; ++rr) {
            Ws[rr] = (l == 0) ? W_src0 + (size_t)rr * 128 * 64
                              : W_src_h + (size_t)((l - 1) * 3 + rr) * 64 * 64;
            Wd[rr] = (l == 0) ? W_dst0 + (size_t)rr * 128 * 64
                              : W_dst_h + (size_t)((l - 1) * 3 + rr) * 64 * 64;
            aS[rr] = att_src + (size_t)(l * 3 + rr) * 64;
            aD[rr] = att_dst + (size_t)(l * 3 + rr) * 64;
        }
        k_pack_store<<<(K * 144 + 255) / 256, 256, 0, stream>>>(
            Ws[0], Ws[2], Wd[1], Wd[2], aS[0], aS[2], aD[1], aD[2], K, panelS[l]);
        k_pack_dept<<<(K * 80 + 255) / 256, 256, 0, stream>>>(
            Ws[1], Wd[0], aD[0], aS[1], K, panelD[l]);

        int gbS = (N_STORE / 16 * 64 + 255) / 256;
        int gbD = (N_DEPT / 16 * 64 + 255) / 256;
        if (l == 0) {
            k_gemm<4, 1, 0><<<gbS, 256, 0, stream>>>(x_store, N_STORE, K, panelS[l],
                                                     hS0, hS2, alsS0, alsS2, aldS12);
            k_gemm<4, 1, 1><<<gbD, 256, 0, stream>>>(x_dept, N_DEPT, K, panelD[l],
                                                     hD, nullptr, aldD0, alsD1, nullptr);
        } else if (l == 1) {
            k_gemm<2, 0, 0><<<gbS, 256, 0, stream>>>(actSA, N_STORE, K, panelS[l],
                                                     hS0, hS2, alsS0, alsS2, aldS12);
            k_gemm<2, 0, 1><<<gbD, 256, 0, stream>>>(actDA, N_DEPT, K, panelD[l],
                                                     hD, nullptr, aldD0, alsD1, nullptr);
        } else {
            k_gemm<2, 0, 0><<<gbS, 256, 0, stream>>>(actSB, N_STORE, K, panelS[l],
                                                     hS0, hS2, alsS0, alsS2, aldS12);
            k_gemm<2, 0, 1><<<gbD, 256, 0, stream>>>(actDB, N_DEPT, K, panelD[l],
                                                     hD, nullptr, aldD0, alsD1, nullptr);
        }

        int relu = (l < 2) ? 1 : 0;
        u16* bS = (l == 0) ? actSA : actSB;
        u16* bD = (l == 0) ? actDA : actDB;
        float* fS = (l == 2) ? outStoreF : nullptr;
        float* fD = (l == 2) ? outDeptF  : nullptr;
        // r0: store -> dept (final write), 2 waves per dept node
        k_agg1<<<N_DEPT / 2, 256, 0, stream>>>(
            off_sd, srcs_all, hS0, alsS0, aldD0,
            bias + (size_t)(l * 3 + 0) * 64, relu, bD, fD);
        // fused r1+r2 -> store output (single write)
        k_agg2<<<N_STORE / 4, 256, 0, stream>>>(
            off_ds, srcs_all, off_ss,
            hD, alsD1, hS2, alsS2, aldS12,
            bias + (size_t)(l * 3 + 1) * 64, bias + (size_t)(l * 3 + 2) * 64,
            relu, bS, fS);
    }
    (void)n_in; (void)out_size; (void)ws_size;
}